// Round 16
// baseline (340.420 us; speedup 1.0000x reference)
//
#include <hip/hip_runtime.h>

// ---------------- types / helpers ----------------
typedef short bf8s __attribute__((ext_vector_type(8)));   // 8 bf16 (4 VGPRs)
typedef float f32x4 __attribute__((ext_vector_type(4)));

#define MFMA16(a, b, c) __builtin_amdgcn_mfma_f32_16x16x32_bf16(a, b, c, 0, 0, 0)

constexpr int S_ = 512, HID_ = 128, B_ = 128, M_ = B_ * S_;
// 0.125 (1/sqrt(64)) * log2(e): Q pre-scale so softmax uses native exp2
constexpr float QSC_ = 0.18033688f;

__device__ inline short f2bf(float f) {  // fp32 -> bf16 (RNE)
  unsigned u = __float_as_uint(f);
  u = (u + 0x7fffu + ((u >> 16) & 1u)) >> 16;
  return (short)u;
}
__device__ inline float bf2f(short s) {
  return __uint_as_float(((unsigned)(unsigned short)s) << 16);
}

__device__ inline float block_red1024(float v, float* red) {
  #pragma unroll
  for (int m = 32; m >= 1; m >>= 1) v += __shfl_xor(v, m);
  __syncthreads();
  if ((threadIdx.x & 63) == 0) red[threadIdx.x >> 6] = v;
  __syncthreads();
  float t = 0.f;
  #pragma unroll
  for (int i = 0; i < 16; ++i) t += red[i];
  return t;
}

// matrix table. doff layout (shorts):
//  per-layer QKV contiguous: l*49152 + {q:0,k:16384,v:32768}
//  ao: 98304 + l*16384 ; iw: 131072 + l*65536 ; fow: 262144 + l*65536 ; clf: 393216
__device__ inline void mat_info(int mat, const float* qw, const float* kw,
                                const float* vw, const float* aow, const float* iw,
                                const float* fw, const float* cw,
                                const float** src, int* n, int* doff) {
  if (mat < 6) {
    int l = mat / 3, which = mat % 3;
    const float* t[3] = {qw, kw, vw};
    *src = t[which] + l * 16384; *n = 16384; *doff = l * 49152 + which * 16384;
  } else if (mat < 8) {
    int l = mat - 6;
    *src = aow + l * 16384; *n = 16384; *doff = 98304 + l * 16384;
  } else if (mat < 10) {
    *src = iw + (mat - 8) * 65536; *n = 65536; *doff = 131072 + (mat - 8) * 65536;
  } else if (mat < 12) {
    *src = fw + (mat - 10) * 65536; *n = 65536; *doff = 262144 + (mat - 10) * 65536;
  } else {
    *src = cw; *n = 256; *doff = 393216;
  }
}

// ---------------- fused quant (blocks 0..12) + embed (blocks 13..) ----------------
__global__ __launch_bounds__(1024) void k_qe(const float* qw, const float* kw,
    const float* vw, const float* aow, const float* iw, const float* fw,
    const float* cw, short* WQ,
    const int* __restrict__ ids, const float* __restrict__ tok,
    const float* __restrict__ pos, const float* __restrict__ g,
    const float* __restrict__ bb, short* xb) {
  __shared__ float red[16];
  int tid = threadIdx.x;
  if (blockIdx.x < 13) {  // ---- ternary quantization ----
    const float* src; int n, doff;
    mat_info(blockIdx.x, qw, kw, vw, aow, iw, fw, cw, &src, &n, &doff);
    float s = 0.f;
    for (int i = tid; i < n; i += 1024) s += fabsf(src[i]);
    s = block_red1024(s, red);
    float delta = 0.7f * s / (float)n;
    float s2 = 0.f, c2 = 0.f;
    for (int i = tid; i < n; i += 1024) {
      float a = fabsf(src[i]);
      if (a > delta) { s2 += a; c2 += 1.f; }
    }
    s2 = block_red1024(s2, red);
    c2 = block_red1024(c2, red);
    float alpha = s2 / fmaxf(c2, 1.f);
    for (int i = tid; i < n; i += 1024) {
      float w = src[i];
      WQ[doff + i] = (fabsf(w) > delta) ? f2bf(w > 0.f ? alpha : -alpha) : (short)0;
    }
  } else {  // ---- embedding + LN ----
    int wave = tid >> 6, lane = tid & 63;
    int t = (blockIdx.x - 13) * 16 + wave;
    int s = t & (S_ - 1);
    int id = ids[t];
    float e0 = tok[(size_t)id * HID_ + lane] + pos[(size_t)s * HID_ + lane];
    float e1 = tok[(size_t)id * HID_ + 64 + lane] + pos[(size_t)s * HID_ + 64 + lane];
    float sum = e0 + e1, ssq = e0 * e0 + e1 * e1;
    #pragma unroll
    for (int m = 32; m >= 1; m >>= 1) {
      sum += __shfl_xor(sum, m);
      ssq += __shfl_xor(ssq, m);
    }
    float mean = sum / 128.f;
    float var = ssq / 128.f - mean * mean;
    float rs = rsqrtf(var + 1e-5f);
    size_t o = (size_t)t * HID_;
    xb[o + lane]      = f2bf((e0 - mean) * rs * g[lane] + bb[lane]);
    xb[o + 64 + lane] = f2bf((e1 - mean) * rs * g[64 + lane] + bb[64 + lane]);
  }
}

// ---------------- QKV linear (layer 0 only): 64-tok blocks, stride-144 LDS ----------------
__global__ __launch_bounds__(256) void k_qkv(
    const short* __restrict__ A, const short* __restrict__ W,
    const float* __restrict__ b0, const float* __restrict__ b1,
    const float* __restrict__ b2, short* outb) {
  __shared__ short Wl[128 * 144];  // 144 shorts = 72 words (8 mod 32): 4-way not 8-way
  int tid = threadIdx.x, lane = tid & 63, wave = tid >> 6;
  int row16 = lane & 15, quad = lane >> 4;
  int tok0 = blockIdx.x * 64 + wave * 16;
  int nbase = blockIdx.y * 128;

  const short* arow = A + (size_t)(tok0 + row16) * 128 + quad * 8;
  bf8s av[4];
  #pragma unroll
  for (int ki = 0; ki < 4; ++ki) av[ki] = *(const bf8s*)(arow + ki * 32);

  {
    int r = tid >> 1, half = tid & 1;
    const short* src = W + (size_t)(nbase + r) * 128 + half * 64;
    short* dst = &Wl[r * 144 + half * 64];
    #pragma unroll
    for (int j = 0; j < 8; ++j)
      *(bf8s*)(dst + j * 8) = *(const bf8s*)(src + j * 8);
  }
  __syncthreads();

  f32x4 acc[8] = {};
  #pragma unroll
  for (int ki = 0; ki < 4; ++ki)
    #pragma unroll
    for (int ot = 0; ot < 8; ++ot) {
      bf8s b = *(const bf8s*)(&Wl[(ot * 16 + row16) * 144 + ki * 32 + quad * 8]);
      acc[ot] = MFMA16(av[ki], b, acc[ot]);
    }

  const float* bp = (blockIdx.y == 0) ? b0 : ((blockIdx.y == 1) ? b1 : b2);
  float osc = (blockIdx.y == 0) ? QSC_ : 1.0f;  // fold 1/sqrt(64)*log2(e) into Q
  int m0 = tok0 + quad * 4;
  #pragma unroll
  for (int ot = 0; ot < 8; ++ot) {
    int col = ot * 16 + row16;
    float bi = bp[col];
    #pragma unroll
    for (int r = 0; r < 4; ++r) {
      float v = (acc[ot][r] + bi) * osc;
      outb[(size_t)(m0 + r) * 384 + nbase + col] = f2bf(v);
    }
  }
}

// ---------------- fused AO+LN1+FF1+FF2+LN2 [+ next-layer QKV] ----------------
// 512 threads / 128 tokens (grid 512 = exactly 2 blocks/CU). Round 13-15
// structure; spill accepted (three de-spill attempts all neutral/ignored).
template <int DOQKV>
__global__ __launch_bounds__(512, 2) void k_aoff(
    const short* __restrict__ cb, const short* __restrict__ Wa,
    const float* __restrict__ aob, const float* __restrict__ ln1g,
    const float* __restrict__ ln1b, const short* __restrict__ Wi,
    const short* __restrict__ Wf, const float* __restrict__ ib,
    const float* __restrict__ fb, const float* __restrict__ ln2g,
    const float* __restrict__ ln2b, short* xb,
    const short* __restrict__ Wqkv2, const float* __restrict__ qb2,
    const float* __restrict__ kb2, const float* __restrict__ vb2,
    short* qkvout) {
  __shared__ short SM[29696];
  int tid = threadIdx.x, lane = tid & 63, wave = tid >> 6;
  int row16 = lane & 15, quad = lane >> 4;
  int tok0 = blockIdx.x * 128 + wave * 16;
  int m0 = tok0 + quad * 4;

  // ---- phase A: AO linear ----
  const short* arow = cb + (size_t)(tok0 + row16) * 128 + quad * 8;
  bf8s av[4];
  #pragma unroll
  for (int ki = 0; ki < 4; ++ki) av[ki] = *(const bf8s*)(arow + ki * 32);

  {  // stage Wa 128x128 (stride 144): 4 threads/row, 32 shorts each
    int r = tid >> 2, q4 = tid & 3;
    const short* src = Wa + (size_t)r * 128 + q4 * 32;
    short* dst = &SM[r * 144 + q4 * 32];
    #pragma unroll
    for (int j = 0; j < 4; ++j)
      *(bf8s*)(dst + j * 8) = *(const bf8s*)(src + j * 8);
  }
  __syncthreads();

  f32x4 acc[8] = {};
  #pragma unroll
  for (int ki = 0; ki < 4; ++ki)
    #pragma unroll
    for (int ot = 0; ot < 8; ++ot) {
      bf8s b = *(const bf8s*)(&SM[(ot * 16 + row16) * 144 + ki * 32 + quad * 8]);
      acc[ot] = MFMA16(av[ki], b, acc[ot]);
    }

  // AO epilogue: bias + residual + LN1 -> x'
  {
    float sum[4] = {}, ssq[4] = {};
    #pragma unroll
    for (int ot = 0; ot < 8; ++ot) {
      int col = ot * 16 + row16;
      float bi = aob[col];
      #pragma unroll
      for (int r = 0; r < 4; ++r) {
        float v = acc[ot][r] + bi + bf2f(xb[(size_t)(m0 + r) * HID_ + col]);
        acc[ot][r] = v;
        sum[r] += v; ssq[r] += v * v;
      }
    }
    #pragma unroll
    for (int m = 1; m <= 8; m <<= 1)
      #pragma unroll
      for (int r = 0; r < 4; ++r) {
        sum[r] += __shfl_xor(sum[r], m);
        ssq[r] += __shfl_xor(ssq[r], m);
      }
    float mean[4], rstd[4];
    #pragma unroll
    for (int r = 0; r < 4; ++r) {
      mean[r] = sum[r] / 128.f;
      float var = ssq[r] / 128.f - mean[r] * mean[r];
      rstd[r] = rsqrtf(var + 1e-5f);
    }
    #pragma unroll
    for (int ot = 0; ot < 8; ++ot) {
      int col = ot * 16 + row16;
      float gg = ln1g[col], bb2 = ln1b[col];
      #pragma unroll
      for (int r = 0; r < 4; ++r)
        acc[ot][r] = (acc[ot][r] - mean[r]) * rstd[r] * gg + bb2;  // x'
    }
  }

  // spill x' (bf16) to xb's own rows (dead until FF epilogue) -> frees acc regs
  #pragma unroll
  for (int ot = 0; ot < 8; ++ot) {
    int col = ot * 16 + row16;
    #pragma unroll
    for (int r = 0; r < 4; ++r)
      xb[(size_t)(m0 + r) * HID_ + col] = f2bf(acc[ot][r]);
  }

  // transpose x' -> A-frags through the (dead) Wa region; wave-private slice
  __syncthreads();
  {
    short* myX = &SM[wave * 2304];  // 16 rows x stride 144
    #pragma unroll
    for (int ot = 0; ot < 8; ++ot)
      #pragma unroll
      for (int r = 0; r < 4; ++r)
        myX[(quad * 4 + r) * 144 + ot * 16 + row16] = f2bf(acc[ot][r]);
    #pragma unroll
    for (int ki = 0; ki < 4; ++ki)
      av[ki] = *(const bf8s*)(myX + row16 * 144 + ki * 32 + quad * 8);
  }

  // ---- phase B: FF over 8 inter-chunks (direct global->LDS staging) ----
  int rwi = tid >> 3, q8 = tid & 7;   // Wi: 64 rows x 8 groups of 16 shorts
  int rwf = tid >> 2, qf4 = tid & 3;  // Wf: 128 rows x 4 groups of 16 shorts
  short* SWi = SM;                         // 64 x 144
  short* SWf = SM + 9216;                  // 128 x 80
  short* mySt = SM + 19456 + wave * 1280;  // 16 x 80 per wave
  f32x4 acc2[8] = {};
  for (int c = 0; c < 8; ++c) {
    __syncthreads();  // c==0: myX reads done; else: previous SWi/SWf reads done
    {  // stage Wi+Wf chunk: all 4 global loads issued before any LDS write
      const short* ws1 = Wi + (size_t)(c * 64 + rwi) * HID_ + q8 * 16;
      const short* ws2 = Wf + (size_t)rwf * 512 + c * 64 + qf4 * 16;
      bf8s a0 = *(const bf8s*)(ws1);
      bf8s a1 = *(const bf8s*)(ws1 + 8);
      bf8s b0 = *(const bf8s*)(ws2);
      bf8s b1 = *(const bf8s*)(ws2 + 8);
      short* dwi = SWi + rwi * 144 + q8 * 16;
      short* dwf = SWf + rwf * 80 + qf4 * 16;
      *(bf8s*)(dwi) = a0; *(bf8s*)(dwi + 8) = a1;
      *(bf8s*)(dwf) = b0; *(bf8s*)(dwf + 8) = b1;
    }
    __syncthreads();

    // FF1 sequentialized: one 16x16 tile at a time
    #pragma unroll
    for (int ot = 0; ot < 4; ++ot) {
      f32x4 hacc = {};
      #pragma unroll
      for (int ki = 0; ki < 4; ++ki) {
        bf8s b = *(const bf8s*)(SWi + (ot * 16 + row16) * 144 + ki * 32 + quad * 8);
        hacc = MFMA16(av[ki], b, hacc);
      }
      float bi = ib[c * 64 + ot * 16 + row16];
      #pragma unroll
      for (int r = 0; r < 4; ++r)
        mySt[(quad * 4 + r) * 80 + ot * 16 + row16] =
            f2bf(fmaxf(hacc[r] + bi, 0.f));
    }
    bf8s ha0 = *(const bf8s*)(mySt + row16 * 80 + quad * 8);
    bf8s ha1 = *(const bf8s*)(mySt + row16 * 80 + 32 + quad * 8);
    #pragma unroll
    for (int ot = 0; ot < 8; ++ot) {
      bf8s bA = *(const bf8s*)(SWf + (ot * 16 + row16) * 80 + quad * 8);
      bf8s bB = *(const bf8s*)(SWf + (ot * 16 + row16) * 80 + 32 + quad * 8);
      acc2[ot] = MFMA16(ha0, bA, acc2[ot]);
      acc2[ot] = MFMA16(ha1, bB, acc2[ot]);
    }
  }

  // FF epilogue: + fb + x'(from xb) + LN2 -> x'' in acc2; write xb
  {
    float sum[4] = {}, ssq[4] = {};
    #pragma unroll
    for (int ot = 0; ot < 8; ++ot) {
      int col = ot * 16 + row16;
      float bi = fb[col];
      #pragma unroll
      for (int r = 0; r < 4; ++r) {
        float v = acc2[ot][r] + bi + bf2f(xb[(size_t)(m0 + r) * HID_ + col]);
        acc2[ot][r] = v;
        sum[r] += v; ssq[r] += v * v;
      }
    }
    #pragma unroll
    for (int m = 1; m <= 8; m <<= 1)
      #pragma unroll
      for (int r = 0; r < 4; ++r) {
        sum[r] += __shfl_xor(sum[r], m);
        ssq[r] += __shfl_xor(ssq[r], m);
      }
    float mean[4], rstd[4];
    #pragma unroll
    for (int r = 0; r < 4; ++r) {
      mean[r] = sum[r] / 128.f;
      float var = ssq[r] / 128.f - mean[r] * mean[r];
      rstd[r] = rsqrtf(var + 1e-5f);
    }
    #pragma unroll
    for (int ot = 0; ot < 8; ++ot) {
      int col = ot * 16 + row16;
      float gg = ln2g[col], bb2 = ln2b[col];
      #pragma unroll
      for (int r = 0; r < 4; ++r) {
        float v = (acc2[ot][r] - mean[r]) * rstd[r] * gg + bb2;
        acc2[ot][r] = v;
        xb[(size_t)(m0 + r) * HID_ + col] = f2bf(v);
      }
    }
  }

  if (DOQKV) {
    // ---- tail: next-layer QKV for our own 128 tokens ----
    __syncthreads();  // all FF LDS reads done
    bf8s av2[4];
    {
      short* myX = &SM[wave * 2304];  // 16 rows x stride 144
      #pragma unroll
      for (int ot = 0; ot < 8; ++ot)
        #pragma unroll
        for (int r = 0; r < 4; ++r)
          myX[(quad * 4 + r) * 144 + ot * 16 + row16] = f2bf(acc2[ot][r]);
      #pragma unroll
      for (int ki = 0; ki < 4; ++ki)
        av2[ki] = *(const bf8s*)(myX + row16 * 144 + ki * 32 + quad * 8);
    }
    for (int c3 = 0; c3 < 3; ++c3) {
      __syncthreads();  // protects myX (c3==0) / previous chunk reads
      {  // stage Wqkv chunk 128x128 (stride 144): 4 threads/row
        int r = tid >> 2, q4 = tid & 3;
        const short* src = Wqkv2 + (size_t)(c3 * 128 + r) * 128 + q4 * 32;
        short* dst = &SM[r * 144 + q4 * 32];
        #pragma unroll
        for (int j = 0; j < 4; ++j)
          *(bf8s*)(dst + j * 8) = *(const bf8s*)(src + j * 8);
      }
      __syncthreads();
      f32x4 acc3[8] = {};
      #pragma unroll
      for (int ki = 0; ki < 4; ++ki)
        #pragma unroll
        for (int ot = 0; ot < 8; ++ot) {
          bf8s b = *(const bf8s*)(&SM[(ot * 16 + row16) * 144 + ki * 32 + quad * 8]);
          acc3[ot] = MFMA16(av2[ki], b, acc3[ot]);
        }
      const float* bp = (c3 == 0) ? qb2 : ((c3 == 1) ? kb2 : vb2);
      float osc = (c3 == 0) ? QSC_ : 1.0f;
      #pragma unroll
      for (int ot = 0; ot < 8; ++ot) {
        int col = ot * 16 + row16;
        float bi = bp[col];
        #pragma unroll
        for (int r = 0; r < 4; ++r) {
          float v = (acc3[ot][r] + bi) * osc;
          qkvout[(size_t)(m0 + r) * 384 + c3 * 128 + col] = f2bf(v);
        }
      }
    }
  }
}

// ---------------- flash attention: 1 q-frag/wave, 32 waves/CU ----------------
// Round-15 diagnosis: 2-qf version had grid 512 x 8 waves = 16 waves/CU —
// GRID-limited to half capacity (Occupancy ~19%) while all pipes idle.
// Now: wave = 16 queries (1 q-frag), grid 1024 = (b<<3)|(h<<2)|qq, block 512
// (8 waves) -> 8192 waves = 32 waves/CU. LDS unchanged 36864 B (4 blocks/CU).
// Persistent regs: qa 8 + oacc 16 + li 4 + kst/vst 8 ~ 36 -> no spill at 64.
// Softmax via native exp2 (Q pre-scaled by 0.125*log2e). li per-lane partials,
// reduced once in epilogue.
__global__ __launch_bounds__(512) void k_attn(const short* __restrict__ qkv,
                                              short* __restrict__ O) {
  __shared__ short Kl[64 * 72];     // 64 keys x 64 d, stride 72
  __shared__ short Vtl[64 * 72];    // 64 d x 64 keys, stride 72
  __shared__ short Pl[8][16 * 72];  // per-wave P stash (16 q x 64 k)

  int tid = threadIdx.x, lane = tid & 63, wave = tid >> 6;
  int row16 = lane & 15, quad = lane >> 4;
  int b = blockIdx.x >> 3, h = (blockIdx.x >> 2) & 1, qq = blockIdx.x & 3;
  const short* base  = qkv + (size_t)b * S_ * 384;
  const short* kbase = base + 128 + h * 64;
  const short* vbase = base + 256 + h * 64;
  int q0 = qq * 128 + wave * 16;

  const short* qrow = base + h * 64 + (size_t)(q0 + row16) * 384 + quad * 8;
  bf8s qa0 = *(const bf8s*)(qrow);
  bf8s qa1 = *(const bf8s*)(qrow + 32);

  int krow = tid >> 3, dgk = tid & 7;
  int vkey = tid & 63, dgv = tid >> 6;
  const short* kptr = kbase + (size_t)krow * 384 + dgk * 8;
  const short* vptr = vbase + (size_t)vkey * 384 + dgv * 8;
  bf8s kst = *(const bf8s*)(kptr);
  bf8s vst = *(const bf8s*)(vptr);

  float li[4] = {};
  f32x4 oacc[4] = {};
  short* myP = &Pl[wave][0];

  for (int kt0 = 0; kt0 < S_; kt0 += 64) {
    if (kt0) __syncthreads();
    *(bf8s*)(&Kl[krow * 72 + dgk * 8]) = kst;
    #pragma unroll
    for (int j = 0; j < 8; ++j) Vtl[(dgv * 8 + j) * 72 + vkey] = vst[j];
    __syncthreads();
    if (kt0 + 64 < S_) {  // prefetch next stage
      kst = *(const bf8s*)(kptr + (size_t)(kt0 + 64) * 384);
      vst = *(const bf8s*)(vptr + (size_t)(kt0 + 64) * 384);
    }

    f32x4 sc[4] = {};
    #pragma unroll
    for (int ks = 0; ks < 4; ++ks) {
      const short* kp = &Kl[(ks * 16 + row16) * 72 + quad * 8];
      bf8s k0 = *(const bf8s*)(kp);
      bf8s k1 = *(const bf8s*)(kp + 32);
      sc[ks] = MFMA16(qa0, k0, sc[ks]);
      sc[ks] = MFMA16(qa1, k1, sc[ks]);
    }

    #pragma unroll
    for (int ks = 0; ks < 4; ++ks)
      #pragma unroll
      for (int r = 0; r < 4; ++r) {
        float pv = exp2f(sc[ks][r]);
        li[r] += pv;  // per-lane partial; cross-lane reduce deferred
        myP[(quad * 4 + r) * 72 + ks * 16 + row16] = f2bf(pv);
      }
    bf8s pa0 = *(const bf8s*)(&myP[row16 * 72 + quad * 8]);
    bf8s pa1 = *(const bf8s*)(&myP[row16 * 72 + 32 + quad * 8]);
    #pragma unroll
    for (int dt = 0; dt < 4; ++dt) {
      const short* vp = &Vtl[(dt * 16 + row16) * 72 + quad * 8];
      bf8s v0 = *(const bf8s*)(vp);
      bf8s v1 = *(const bf8s*)(vp + 32);
      oacc[dt] = MFMA16(pa0, v0, oacc[dt]);
      oacc[dt] = MFMA16(pa1, v1, oacc[dt]);
    }
  }

  float inv[4];
  #pragma unroll
  for (int r = 0; r < 4; ++r) {
    float t = li[r];
    #pragma unroll
    for (int m = 1; m <= 8; m <<= 1) t += __shfl_xor(t, m);
    inv[r] = 1.f / t;
  }
  size_t trow = (size_t)(b * S_ + q0 + quad * 4);
  #pragma unroll
  for (int dt = 0; dt < 4; ++dt)
    #pragma unroll
    for (int r = 0; r < 4; ++r)
      O[(trow + r) * HID_ + h * 64 + dt * 16 + row16] =
          f2bf(oacc[dt][r] * inv[r]);
}

// ---------------- classifier ----------------
__global__ __launch_bounds__(256) void k_clf(const short* __restrict__ xb,
    const short* __restrict__ Wc, const float* __restrict__ cbias, float* out) {
  int i = threadIdx.x;  // 256 = 128 batches x 2 classes
  int b = i >> 1, c = i & 1;
  float s = 0.f;
  for (int k = 0; k < HID_; ++k)
    s += bf2f(xb[(size_t)b * S_ * HID_ + k]) * bf2f(Wc[c * HID_ + k]);
  out[b * 2 + c] = s + cbias[c];
}

// ---------------- launcher ----------------
extern "C" void kernel_launch(void* const* d_in, const int* in_sizes, int n_in,
                              void* d_out, int out_size, void* d_ws, size_t ws_size,
                              hipStream_t stream) {
  const int*   ids     = (const int*)d_in[0];
  const float* tok_emb = (const float*)d_in[1];
  const float* pos_emb = (const float*)d_in[2];
  const float* ln_g    = (const float*)d_in[3];
  const float* ln_bb   = (const float*)d_in[4];
  const float* qw      = (const float*)d_in[5];
  const float* qbias   = (const float*)d_in[6];
  const float* kw      = (const float*)d_in[7];
  const float* kbias   = (const float*)d_in[8];
  const float* vw      = (const float*)d_in[9];
  const float* vbias   = (const float*)d_in[10];
  const float* aow     = (const float*)d_in[11];
  const float* aobias  = (const float*)d_in[12];
  const float* iw      = (const float*)d_in[13];
  const float* ibias   = (const float*)d_in[14];
  const float* fow     = (const float*)d_in[15];
  const float* fbias   = (const float*)d_in[16];
  const float* ln1g    = (const float*)d_in[17];
  const float* ln1b    = (const float*)d_in[18];
  const float* ln2g    = (const float*)d_in[19];
  const float* ln2b    = (const float*)d_in[20];
  const float* clfw    = (const float*)d_in[21];
  const float* clfb    = (const float*)d_in[22];

  char* ws = (char*)d_ws;
  short* WQ  = (short*)ws;                                   // 787 KB quantized weights
  short* xb  = (short*)(ws + 1048576);                       // bf16 trunk (16.8 MB)
  short* qkv = (short*)(ws + 1048576 + 16777216);            // [tok][384] (50.3 MB)
  short* cb_ = qkv + (size_t)M_ * 384;                       // ctx [tok][128] (16.8 MB)

  k_qe<<<13 + M_ / 16, 1024, 0, stream>>>(qw, kw, vw, aow, iw, fow, clfw, WQ,
                                          ids, tok_emb, pos_emb, ln_g, ln_bb, xb);

  const short* Wqkv0 = WQ;
  const short* Wqkv1 = WQ + 49152;
  const short* Wa0   = WQ + 98304;
  const short* Wa1   = WQ + 98304 + 16384;
  const short* Wi0   = WQ + 131072;
  const short* Wi1   = WQ + 131072 + 65536;
  const short* Wf0   = WQ + 262144;
  const short* Wf1   = WQ + 262144 + 65536;

  // layer 0 (k_aoff tail computes layer-1 QKV)
  k_qkv<<<dim3(M_ / 64, 3), 256, 0, stream>>>(
      xb, Wqkv0, qbias, kbias, vbias, qkv);
  k_attn<<<1024, 512, 0, stream>>>(qkv, cb_);
  k_aoff<1><<<M_ / 128, 512, 0, stream>>>(
      cb_, Wa0, aobias, ln1g, ln1b, Wi0, Wf0, ibias, fbias, ln2g, ln2b, xb,
      Wqkv1, qbias + HID_, kbias + HID_, vbias + HID_, qkv);
  // layer 1
  k_attn<<<1024, 512, 0, stream>>>(qkv, cb_);
  k_aoff<0><<<M_ / 128, 512, 0, stream>>>(
      cb_, Wa1, aobias + HID_, ln1g + HID_, ln1b + HID_, Wi1, Wf1,
      ibias + 512, fbias + HID_, ln2g + HID_, ln2b + HID_, xb,
      nullptr, nullptr, nullptr, nullptr, nullptr);

  k_clf<<<1, 256, 0, stream>>>(xb, WQ + 393216, clfb, (float*)d_out);
}